// Round 1
// baseline (2765.620 us; speedup 1.0000x reference)
//
#include <hip/hip_runtime.h>
#include <math.h>

#define BEHN 3
#define HN 64
#define SN 262144
#define NUSERS 1000000
#define BN_EPS 1e-5f

__device__ __forceinline__ float sigmoidf_(float x) {
    return 1.f / (1.f + __expf(-x));
}

// wave(64)-level sum of v and v^2, one atomicAdd pair per wave
__device__ __forceinline__ void wave_stat_atomic(float v, float* sum_p, float* sumsq_p) {
    float a = v, b = v * v;
    #pragma unroll
    for (int off = 32; off > 0; off >>= 1) {
        a += __shfl_down(a, off, 64);
        b += __shfl_down(b, off, 64);
    }
    if ((threadIdx.x & 63) == 0) {
        atomicAdd(sum_p, a);
        atomicAdd(sumsq_p, b);
    }
}

__global__ void init_kernel(float* stats) {
    if (threadIdx.x < 24) stats[threadIdx.x] = 0.f;
}

// ---------------- SSL branch: t1 = h1@w2 (scale/shift of BN dropped),
// t3 = prelu(loss * (ue.W3a + u.W3b) + b3). u row shared across behaviors.
__global__ __launch_bounds__(256, 2)
void ssl_kernel(const float* __restrict__ infoNCE,      // [3,S]
                const int* __restrict__ step_idx,       // [S]
                const float* __restrict__ user_embeds,  // [3,N,H]
                const float* __restrict__ user_embed,   // [N,H]
                const float* __restrict__ W1,           // [96,192]
                const float* __restrict__ b1,           // [96]
                const float* __restrict__ W2,           // [96]
                const float* __restrict__ W3,           // [128]
                const float* __restrict__ b3p,          // [1]
                const float* __restrict__ prelu_ap,     // [1]
                float* __restrict__ tbuf,               // ws: 12 arrays of S
                float* __restrict__ stats)              // 24 floats
{
    __shared__ float lw[96 * 128];
    __shared__ float lc1[96], lb1[96], lw2[96], lw3[128];
    const int tid = threadIdx.x;

    // stage W1 cols 64..191 (the emb part) into LDS
    for (int t = tid; t < 96 * 32; t += 256) {
        const int j = t >> 5, q = t & 31;
        ((float4*)lw)[t] = *(const float4*)(W1 + j * 192 + 64 + 4 * q);
    }
    // c1[j] = sum of W1[j,0:64] (the broadcast-loss block), plus small vectors
    for (int t = tid; t < 96; t += 256) {
        float sacc = 0.f;
        const float* row = W1 + t * 192;
        #pragma unroll
        for (int k = 0; k < 64; ++k) sacc += row[k];
        lc1[t] = sacc;
        lb1[t] = b1[t];
        lw2[t] = W2[t];
    }
    if (tid < 32) ((float4*)lw3)[tid] = ((const float4*)W3)[tid];
    __syncthreads();

    const float pa = prelu_ap[0];
    const float b3 = b3p[0];
    const int s = blockIdx.x * 256 + tid;
    const int idx = step_idx[s];

    // u row (shared across behaviors) -> registers
    float e1r[HN];
    {
        const float4* up = (const float4*)(user_embed + (size_t)idx * HN);
        #pragma unroll
        for (int q = 0; q < 16; ++q) {
            const float4 v = up[q];
            e1r[4*q] = v.x; e1r[4*q+1] = v.y; e1r[4*q+2] = v.z; e1r[4*q+3] = v.w;
        }
    }
    // shared part of t3: dot(u, W3[64:128])
    float d0 = 0.f, d1 = 0.f, d2 = 0.f, d3 = 0.f;
    #pragma unroll
    for (int k = 0; k < 64; k += 4) {
        d0 = fmaf(e1r[k],   lw3[64+k],   d0);
        d1 = fmaf(e1r[k+1], lw3[64+k+1], d1);
        d2 = fmaf(e1r[k+2], lw3[64+k+2], d2);
        d3 = fmaf(e1r[k+3], lw3[64+k+3], d3);
    }
    const float du3 = (d0 + d1) + (d2 + d3);

    #pragma unroll 1
    for (int i = 0; i < BEHN; ++i) {
        const float loss = infoNCE[(size_t)i * SN + s];
        float e0r[HN];
        {
            const float4* uep = (const float4*)(user_embeds + ((size_t)i * NUSERS + (size_t)idx) * HN);
            #pragma unroll
            for (int q = 0; q < 16; ++q) {
                const float4 v = uep[q];
                e0r[4*q] = v.x; e0r[4*q+1] = v.y; e0r[4*q+2] = v.z; e0r[4*q+3] = v.w;
            }
        }
        float t1 = 0.f;
        #pragma unroll 2
        for (int j = 0; j < 96; ++j) {
            const float4* wr = (const float4*)(lw + j * 128);
            float h0 = fmaf(loss, lc1[j], lb1[j]);
            float h1 = 0.f, h2 = 0.f, h3 = 0.f;
            #pragma unroll
            for (int q = 0; q < 16; ++q) {
                const float4 w = wr[q];
                h0 = fmaf(w.x, e0r[4*q],   h0);
                h1 = fmaf(w.y, e0r[4*q+1], h1);
                h2 = fmaf(w.z, e0r[4*q+2], h2);
                h3 = fmaf(w.w, e0r[4*q+3], h3);
            }
            #pragma unroll
            for (int q = 0; q < 16; ++q) {
                const float4 w = wr[16 + q];
                h0 = fmaf(w.x, e1r[4*q],   h0);
                h1 = fmaf(w.y, e1r[4*q+1], h1);
                h2 = fmaf(w.z, e1r[4*q+2], h2);
                h3 = fmaf(w.w, e1r[4*q+3], h3);
            }
            const float h = (h0 + h1) + (h2 + h3);
            const float hp = h >= 0.f ? h : pa * h;
            t1 = fmaf(lw2[j], hp, t1);
        }
        // t3
        float g0 = 0.f, g1 = 0.f, g2 = 0.f, g3 = 0.f;
        #pragma unroll
        for (int k = 0; k < 64; k += 4) {
            g0 = fmaf(e0r[k],   lw3[k],   g0);
            g1 = fmaf(e0r[k+1], lw3[k+1], g1);
            g2 = fmaf(e0r[k+2], lw3[k+2], g2);
            g3 = fmaf(e0r[k+3], lw3[k+3], g3);
        }
        float t3 = fmaf(loss, du3 + (g0 + g1) + (g2 + g3), b3);
        t3 = t3 >= 0.f ? t3 : pa * t3;

        tbuf[(size_t)i * SN + s] = t1;
        tbuf[(size_t)(3 + i) * SN + s] = t3;
        wave_stat_atomic(t1, stats + i, stats + 12 + i);
        wave_stat_atomic(t3, stats + 3 + i, stats + 12 + 3 + i);
    }
}

// ---------------- RS branch: rs_in = [bloss_rep, u_r, ue_i_r]; indices differ per behavior
__global__ __launch_bounds__(256, 2)
void rs_kernel(const float* __restrict__ bloss_list,   // [3,S]
               const int* __restrict__ uidx_list,      // [3,S]
               const float* __restrict__ user_embeds,  // [3,N,H]
               const float* __restrict__ user_embed,   // [N,H]
               const float* __restrict__ W1,           // [96,192]
               const float* __restrict__ b1,           // [96]
               const float* __restrict__ W2,           // [96]
               const float* __restrict__ W3,           // [64]
               const float* __restrict__ b3p,          // [1]
               const float* __restrict__ prelu_ap,     // [1]
               float* __restrict__ tbuf,
               float* __restrict__ stats)
{
    __shared__ float lw[96 * 128];
    __shared__ float lc1[96], lb1[96], lw2[96], lw3[64];
    const int tid = threadIdx.x;

    for (int t = tid; t < 96 * 32; t += 256) {
        const int j = t >> 5, q = t & 31;
        ((float4*)lw)[t] = *(const float4*)(W1 + j * 192 + 64 + 4 * q);
    }
    for (int t = tid; t < 96; t += 256) {
        float sacc = 0.f;
        const float* row = W1 + t * 192;
        #pragma unroll
        for (int k = 0; k < 64; ++k) sacc += row[k];
        lc1[t] = sacc;
        lb1[t] = b1[t];
        lw2[t] = W2[t];
    }
    if (tid < 16) ((float4*)lw3)[tid] = ((const float4*)W3)[tid];
    __syncthreads();

    const float pa = prelu_ap[0];
    const float b3 = b3p[0];
    const int s = blockIdx.x * 256 + tid;

    #pragma unroll 1
    for (int i = 0; i < BEHN; ++i) {
        const int idx = uidx_list[(size_t)i * SN + s];
        const float bl = bloss_list[(size_t)i * SN + s];
        // e0 = u_r (cols 64:128 of W1), e1 = ue_i_r (cols 128:192)
        float e0r[HN], e1r[HN];
        {
            const float4* up = (const float4*)(user_embed + (size_t)idx * HN);
            const float4* uep = (const float4*)(user_embeds + ((size_t)i * NUSERS + (size_t)idx) * HN);
            #pragma unroll
            for (int q = 0; q < 16; ++q) {
                const float4 v = up[q];
                e0r[4*q] = v.x; e0r[4*q+1] = v.y; e0r[4*q+2] = v.z; e0r[4*q+3] = v.w;
            }
            #pragma unroll
            for (int q = 0; q < 16; ++q) {
                const float4 v = uep[q];
                e1r[4*q] = v.x; e1r[4*q+1] = v.y; e1r[4*q+2] = v.z; e1r[4*q+3] = v.w;
            }
        }
        float t1 = 0.f;
        #pragma unroll 2
        for (int j = 0; j < 96; ++j) {
            const float4* wr = (const float4*)(lw + j * 128);
            float h0 = fmaf(bl, lc1[j], lb1[j]);
            float h1 = 0.f, h2 = 0.f, h3 = 0.f;
            #pragma unroll
            for (int q = 0; q < 16; ++q) {
                const float4 w = wr[q];
                h0 = fmaf(w.x, e0r[4*q],   h0);
                h1 = fmaf(w.y, e0r[4*q+1], h1);
                h2 = fmaf(w.z, e0r[4*q+2], h2);
                h3 = fmaf(w.w, e0r[4*q+3], h3);
            }
            #pragma unroll
            for (int q = 0; q < 16; ++q) {
                const float4 w = wr[16 + q];
                h0 = fmaf(w.x, e1r[4*q],   h0);
                h1 = fmaf(w.y, e1r[4*q+1], h1);
                h2 = fmaf(w.z, e1r[4*q+2], h2);
                h3 = fmaf(w.w, e1r[4*q+3], h3);
            }
            const float h = (h0 + h1) + (h2 + h3);
            const float hp = h >= 0.f ? h : pa * h;
            t1 = fmaf(lw2[j], hp, t1);
        }
        // t3 = prelu(bl * dot(u_r, W3) + b3)
        float g0 = 0.f, g1 = 0.f, g2 = 0.f, g3 = 0.f;
        #pragma unroll
        for (int k = 0; k < 64; k += 4) {
            g0 = fmaf(e0r[k],   lw3[k],   g0);
            g1 = fmaf(e0r[k+1], lw3[k+1], g1);
            g2 = fmaf(e0r[k+2], lw3[k+2], g2);
            g3 = fmaf(e0r[k+3], lw3[k+3], g3);
        }
        float t3 = fmaf(bl, (g0 + g1) + (g2 + g3), b3);
        t3 = t3 >= 0.f ? t3 : pa * t3;

        tbuf[(size_t)(6 + i) * SN + s] = t1;
        tbuf[(size_t)(9 + i) * SN + s] = t3;
        wave_stat_atomic(t1, stats + 6 + i, stats + 12 + 6 + i);
        wave_stat_atomic(t3, stats + 9 + i, stats + 12 + 9 + i);
    }
}

__global__ void stats_kernel(const float* __restrict__ stats, float* __restrict__ mi) {
    const int a = threadIdx.x;
    if (a < 12) {
        const float inv_n = 1.f / (float)SN;
        const float mean = stats[a] * inv_n;
        float var = stats[12 + a] * inv_n - mean * mean;
        var = fmaxf(var, 0.f);
        mi[a] = mean;
        mi[12 + a] = rsqrtf(var + BN_EPS);
    }
}

__global__ __launch_bounds__(256)
void final_kernel(const float* __restrict__ tbuf, const float* __restrict__ mi,
                  float* __restrict__ out)
{
    const int x = blockIdx.x * 256 + threadIdx.x;  // < 3*SN
    const int i = x / SN;
    const int s = x - i * SN;
    const float w1 = sigmoidf_((tbuf[(size_t)i * SN + s]       - mi[i])     * mi[12 + i]);
    const float w3 = sigmoidf_((tbuf[(size_t)(3 + i) * SN + s] - mi[3 + i]) * mi[12 + 3 + i]);
    const float r1 = sigmoidf_((tbuf[(size_t)(6 + i) * SN + s] - mi[6 + i]) * mi[12 + 6 + i]);
    const float r3 = sigmoidf_((tbuf[(size_t)(9 + i) * SN + s] - mi[9 + i]) * mi[12 + 9 + i]);
    out[(size_t)i * SN + s] = 0.5f * (w1 + w3);
    out[(size_t)3 * SN + (size_t)i * SN + s] = r1 + r3;
}

extern "C" void kernel_launch(void* const* d_in, const int* in_sizes, int n_in,
                              void* d_out, int out_size, void* d_ws, size_t ws_size,
                              hipStream_t stream) {
    (void)in_sizes; (void)n_in; (void)out_size; (void)ws_size;
    const float* infoNCE = (const float*)d_in[0];
    const float* bloss   = (const float*)d_in[1];
    const int*   stepidx = (const int*)d_in[2];
    const int*   uidx    = (const int*)d_in[3];
    const float* uembs   = (const float*)d_in[4];
    const float* uemb    = (const float*)d_in[5];
    const float* W_ssl1  = (const float*)d_in[6];
    const float* b_ssl1  = (const float*)d_in[7];
    const float* W_ssl2  = (const float*)d_in[8];
    // d_in[9] = b_ssl2: cancels inside BN (pure shift)
    const float* W_ssl3  = (const float*)d_in[10];
    const float* b_ssl3  = (const float*)d_in[11];
    const float* W_rs1   = (const float*)d_in[12];
    const float* b_rs1   = (const float*)d_in[13];
    const float* W_rs2   = (const float*)d_in[14];
    // d_in[15] = b_rs2: cancels inside BN
    const float* W_rs3   = (const float*)d_in[16];
    const float* b_rs3   = (const float*)d_in[17];
    const float* pa      = (const float*)d_in[18];

    float* tbuf  = (float*)d_ws;                    // 12 * SN floats
    float* stats = tbuf + (size_t)12 * SN;          // 24 floats (sum[12], sumsq[12])
    float* mi    = stats + 24;                      // 24 floats (mean[12], inv[12])
    float* out   = (float*)d_out;

    hipLaunchKernelGGL(init_kernel, dim3(1), dim3(64), 0, stream, stats);
    hipLaunchKernelGGL(ssl_kernel, dim3(SN / 256), dim3(256), 0, stream,
                       infoNCE, stepidx, uembs, uemb,
                       W_ssl1, b_ssl1, W_ssl2, W_ssl3, b_ssl3, pa, tbuf, stats);
    hipLaunchKernelGGL(rs_kernel, dim3(SN / 256), dim3(256), 0, stream,
                       bloss, uidx, uembs, uemb,
                       W_rs1, b_rs1, W_rs2, W_rs3, b_rs3, pa, tbuf, stats);
    hipLaunchKernelGGL(stats_kernel, dim3(1), dim3(64), 0, stream, stats, mi);
    hipLaunchKernelGGL(final_kernel, dim3((3 * SN) / 256), dim3(256), 0, stream, tbuf, mi, out);
}